// Round 5
// baseline (202.289 us; speedup 1.0000x reference)
//
#include <hip/hip_runtime.h>
#include <float.h>

typedef __bf16 bf16;
typedef __bf16 bf16x8 __attribute__((ext_vector_type(8)));
typedef float f32x4 __attribute__((ext_vector_type(4)));

#define GAS __attribute__((address_space(1)))
#define LAS __attribute__((address_space(3)))

__device__ __forceinline__ void gload_lds16(const void* g, void* l) {
  __builtin_amdgcn_global_load_lds((const GAS unsigned int*)g, (LAS unsigned int*)l, 16, 0, 0);
}

template <int N> struct ic { static constexpr int v = N; };

template <int VM> __device__ __forceinline__ void wait_vmcnt() {
  if constexpr (VM == 0) asm volatile("s_waitcnt vmcnt(0)" ::: "memory");
  else if constexpr (VM == 3) asm volatile("s_waitcnt vmcnt(3)" ::: "memory");
  else if constexpr (VM == 4) asm volatile("s_waitcnt vmcnt(4)" ::: "memory");
  else if constexpr (VM == 6) asm volatile("s_waitcnt vmcnt(6)" ::: "memory");
  else if constexpr (VM == 8) asm volatile("s_waitcnt vmcnt(8)" ::: "memory");
  else if constexpr (VM == 10) asm volatile("s_waitcnt vmcnt(10)" ::: "memory");
}

// ---------------------------------------------------------------------------
// 8-phase GEMM (m201-style): C[M,N] = A[M,K] @ Bt[N,K]^T, bf16 inputs.
// BM=256, BN in {128,256}, K-sub-tile = 32, 4-buffer LDS ring, 8 waves.
// Per sub-tile: 2 phases (N-halves). Per phase: stage-issue (one half of
// sub-tile s+3) -> [counted vmcnt at sub-tile entry] -> s_barrier ->
// ds_read frags -> lgkmcnt(0)+sched_barrier -> setprio(1) MFMA setprio(0)
// -> s_barrier. vmcnt never drains below 10/8 in the main loop; peeled
// tail uses 8/4/0 (BN=256) or 6/3/0 (BN=128).
// 16B-slot XOR swizzle by (row&3); global source pre-swizzled (linear LDS
// dest via global_load_lds), same involution on ds_read.
// ---------------------------------------------------------------------------
template <int OUT_BF16, int BN, int WM, int WN>
__global__ __launch_bounds__(512, 2) void gemm_8ph(
    const bf16* __restrict__ A, const bf16* __restrict__ Bt,
    void* __restrict__ Cv, int M, int N, int K) {
  constexpr int M_rep = 256 / WM / 16;  // 8 (WM=2) or 4 (WM=4)
  constexpr int VMAIN = (BN == 256) ? 10 : 8;
  constexpr int VP0 = (BN == 256) ? 8 : 6;
  constexpr int VP1 = (BN == 256) ? 4 : 3;
  __shared__ __align__(16) bf16 Ab[4][256 * 32];
  __shared__ __align__(16) bf16 Bb[4][BN * 32];

  const int tid = threadIdx.x, lane = tid & 63;
  const int w = tid >> 6, wr = w / WN, wc = w % WN;
  const int g = lane >> 4, fr = lane & 15;

  // bijective XCD-chunked swizzle (m204)
  const int gx = gridDim.x;
  const int nwg = gx * gridDim.y;
  int lid = blockIdx.y * gx + blockIdx.x;
  {
    const int qq = nwg >> 3, rr = nwg & 7;
    const int xcd = lid & 7, pos = lid >> 3;
    lid = (xcd < rr ? xcd * (qq + 1) : rr * (qq + 1) + (xcd - rr) * qq) + pos;
  }
  const int bx = lid % gx, by = lid / gx;
  const size_t m0 = (size_t)by * 256, n0 = (size_t)bx * BN;

  const int ns = K >> 5;  // 32-wide K sub-tiles
  const int srow = tid >> 2, sslot = tid & 3;

  auto stageA = [&](int s) {
    const int b4 = s & 3, kt = s << 5;
#pragma unroll
    for (int c = 0; c < 2; ++c) {
      const int r = c * 128 + srow;
      gload_lds16(A + (m0 + r) * (size_t)K + kt + ((sslot ^ (r & 3)) << 3),
                  &Ab[b4][c * 4096 + tid * 8]);
    }
  };
  auto stageB = [&](int s) {
    const int b4 = s & 3, kt = s << 5;
#pragma unroll
    for (int c = 0; c < BN / 128; ++c) {
      const int r = c * 128 + srow;
      gload_lds16(Bt + (n0 + r) * (size_t)K + kt + ((sslot ^ (r & 3)) << 3),
                  &Bb[b4][c * 4096 + tid * 8]);
    }
  };
  auto rdA = [&](int b4, int mi) {
    const int r = wr * (256 / WM) + mi * 16 + fr;
    return *(const bf16x8*)&Ab[b4][r * 32 + ((g ^ (r & 3)) << 3)];
  };
  auto rdB = [&](int b4, int ni) {
    const int r = wc * 64 + ni * 16 + fr;
    return *(const bf16x8*)&Bb[b4][r * 32 + ((g ^ (r & 3)) << 3)];
  };

  f32x4 acc[M_rep][4] = {};

  auto subtile = [&](int s, auto vmtag, bool doStage) {
    const int b4 = s & 3;
    bf16x8 av[M_rep], bv0, bv1;
    // ---- phase 0 (N-half 0) ----
    if (doStage) stageA(s + 3);
    wait_vmcnt<decltype(vmtag)::v>();
    __builtin_amdgcn_s_barrier();  // all waves: sub-tile s fully landed
    __builtin_amdgcn_sched_barrier(0);
#pragma unroll
    for (int mi = 0; mi < M_rep; ++mi) av[mi] = rdA(b4, mi);
    bv0 = rdB(b4, 0);
    bv1 = rdB(b4, 1);
    asm volatile("s_waitcnt lgkmcnt(0)" ::: "memory");
    __builtin_amdgcn_sched_barrier(0);
    __builtin_amdgcn_s_setprio(1);
#pragma unroll
    for (int mi = 0; mi < M_rep; ++mi) {
      acc[mi][0] = __builtin_amdgcn_mfma_f32_16x16x32_bf16(av[mi], bv0,
                                                           acc[mi][0], 0, 0, 0);
      acc[mi][1] = __builtin_amdgcn_mfma_f32_16x16x32_bf16(av[mi], bv1,
                                                           acc[mi][1], 0, 0, 0);
    }
    __builtin_amdgcn_s_setprio(0);
    __builtin_amdgcn_s_barrier();
    __builtin_amdgcn_sched_barrier(0);
    // ---- phase 1 (N-half 1) ----
    if (doStage) stageB(s + 3);
    __builtin_amdgcn_s_barrier();
    __builtin_amdgcn_sched_barrier(0);
    bv0 = rdB(b4, 2);
    bv1 = rdB(b4, 3);
    asm volatile("s_waitcnt lgkmcnt(0)" ::: "memory");
    __builtin_amdgcn_sched_barrier(0);
    __builtin_amdgcn_s_setprio(1);
#pragma unroll
    for (int mi = 0; mi < M_rep; ++mi) {
      acc[mi][2] = __builtin_amdgcn_mfma_f32_16x16x32_bf16(av[mi], bv0,
                                                           acc[mi][2], 0, 0, 0);
      acc[mi][3] = __builtin_amdgcn_mfma_f32_16x16x32_bf16(av[mi], bv1,
                                                           acc[mi][3], 0, 0, 0);
    }
    __builtin_amdgcn_s_setprio(0);
    __builtin_amdgcn_s_barrier();
    __builtin_amdgcn_sched_barrier(0);
  };

  // prologue: stage sub-tiles 0,1,2 (A then B each)
  stageA(0); stageB(0);
  stageA(1); stageB(1);
  stageA(2); stageB(2);

  for (int s = 0; s < ns - 3; ++s) subtile(s, ic<VMAIN>{}, true);
  subtile(ns - 3, ic<VP0>{}, false);
  subtile(ns - 2, ic<VP1>{}, false);
  subtile(ns - 1, ic<0>{}, false);

#pragma unroll
  for (int mi = 0; mi < M_rep; ++mi)
#pragma unroll
    for (int ni = 0; ni < 4; ++ni)
#pragma unroll
      for (int rg = 0; rg < 4; ++rg) {
        const size_t row = m0 + wr * (256 / WM) + mi * 16 + g * 4 + rg;
        const size_t col = n0 + wc * 64 + ni * 16 + fr;
        if (OUT_BF16)
          ((bf16*)Cv)[row * (size_t)N + col] = (bf16)acc[mi][ni][rg];
        else
          ((float*)Cv)[row * (size_t)N + col] = acc[mi][ni][rg];
      }
}

// ---------------------------------------------------------------------------
// Small GEMM (KV projection): m97-style 128x128 tile, BK=32.
// ---------------------------------------------------------------------------
template <int OUT_BF16>
__global__ __launch_bounds__(256, 2) void gemm_bt(
    const bf16* __restrict__ A, const bf16* __restrict__ Bt,
    void* __restrict__ Cv, int M, int N, int K) {
  __shared__ bf16 As[128 * 32];
  __shared__ bf16 Bs[128 * 32];
  const int tid = threadIdx.x;
  const int lane = tid & 63, w = tid >> 6;
  const int wr = w >> 1, wc = w & 1;

  const int gx = gridDim.x;
  const int nwg = gx * gridDim.y;
  int lid = blockIdx.y * gx + blockIdx.x;
  {
    const int qq = nwg >> 3, rr = nwg & 7;
    const int xcd = lid & 7, pos = lid >> 3;
    lid = (xcd < rr ? xcd * (qq + 1) : rr * (qq + 1) + (xcd - rr) * qq) + pos;
  }
  const int bx = lid % gx, by = lid / gx;
  const size_t m0 = (size_t)by * 128, n0 = (size_t)bx * 128;

  const int srow = lane >> 2, sslot = lane & 3;
  const int g = lane >> 4, fr = lane & 15;

  f32x4 acc[4][4] = {};

  for (int kt = 0; kt < K; kt += 32) {
    __syncthreads();
#pragma unroll
    for (int j = 0; j < 2; ++j) {
      const int c = 2 * w + j;
      const int r = c * 16 + srow;
      const int ks = (sslot ^ (r & 3)) << 3;
      gload_lds16(A + (m0 + r) * K + kt + ks, &As[c * 512]);
      gload_lds16(Bt + (n0 + r) * K + kt + ks, &Bs[c * 512]);
    }
    __syncthreads();
    bf16x8 av[4], bv[4];
#pragma unroll
    for (int mi = 0; mi < 4; ++mi) {
      const int r = wr * 64 + mi * 16 + fr;
      av[mi] = *(const bf16x8*)&As[r * 32 + ((g ^ (r & 3)) << 3)];
    }
#pragma unroll
    for (int ni = 0; ni < 4; ++ni) {
      const int r = wc * 64 + ni * 16 + fr;
      bv[ni] = *(const bf16x8*)&Bs[r * 32 + ((g ^ (r & 3)) << 3)];
    }
#pragma unroll
    for (int mi = 0; mi < 4; ++mi)
#pragma unroll
      for (int ni = 0; ni < 4; ++ni)
        acc[mi][ni] = __builtin_amdgcn_mfma_f32_16x16x32_bf16(
            av[mi], bv[ni], acc[mi][ni], 0, 0, 0);
  }

#pragma unroll
  for (int mi = 0; mi < 4; ++mi)
#pragma unroll
    for (int ni = 0; ni < 4; ++ni)
#pragma unroll
      for (int rg = 0; rg < 4; ++rg) {
        const size_t row = m0 + wr * 64 + mi * 16 + g * 4 + rg;
        const size_t col = n0 + wc * 64 + ni * 16 + fr;
        if (OUT_BF16)
          ((bf16*)Cv)[row * (size_t)N + col] = (bf16)acc[mi][ni][rg];
        else
          ((float*)Cv)[row * (size_t)N + col] = acc[mi][ni][rg];
      }
}

// ---------------------------------------------------------------------------
// Coalesced 64x64 LDS-tiled transpose: dst[C][R] = src[R][C] * scale (bf16)
// ---------------------------------------------------------------------------
__device__ __forceinline__ void transp64(const float* __restrict__ src,
                                         bf16* __restrict__ dst, int R, int C,
                                         float scale, int tile, float* lds) {
  const int tilesC = C >> 6;
  const int tr = tile / tilesC, tc = tile % tilesC;
  const int r0 = tr << 6, c0 = tc << 6;
  const int tid = threadIdx.x;
  const int lr = tid >> 6, lc = tid & 63;
#pragma unroll
  for (int j = 0; j < 16; ++j) {
    const int r = j * 4 + lr;
    lds[r * 65 + lc] = src[(size_t)(r0 + r) * C + c0 + lc];
  }
  __syncthreads();
#pragma unroll
  for (int j = 0; j < 16; ++j) {
    const int rr = j * 4 + lr;  // dst row = src col
    dst[(size_t)(c0 + rr) * R + r0 + lc] = (bf16)(lds[lc * 65 + rr] * scale);
  }
}

// ---------------------------------------------------------------------------
// Mega prep kernel: one launch, block-range partitioned.
// ---------------------------------------------------------------------------
__global__ __launch_bounds__(256) void prep_all(
    const float* __restrict__ x, const float* __restrict__ gamma,
    const float* __restrict__ beta, bf16* __restrict__ xn,
    const float* __restrict__ Wq, bf16* __restrict__ wqT,
    const float* __restrict__ Wkv, bf16* __restrict__ wkvT,
    const float* __restrict__ Wout, bf16* __restrict__ woT,
    const float* __restrict__ media, bf16* __restrict__ medb,
    const int* __restrict__ mloc, int* __restrict__ endw,
    const unsigned char* __restrict__ mraw, int* __restrict__ mk) {
  __shared__ float shf[64 * 65];
  const int blk = blockIdx.x, tid = threadIdx.x;

  if (blk < 16384) {
    const size_t base = (size_t)blk * 2048 + tid * 8;
    f32x4 v0 = *(const f32x4*)(x + base);
    f32x4 v1 = *(const f32x4*)(x + base + 4);
    float s = 0.f, q2 = 0.f;
#pragma unroll
    for (int j = 0; j < 4; ++j) {
      s += v0[j] + v1[j];
      q2 += v0[j] * v0[j] + v1[j] * v1[j];
    }
    for (int off = 32; off > 0; off >>= 1) {
      s += __shfl_down(s, off);
      q2 += __shfl_down(q2, off);
    }
    const int lane = tid & 63, wv = tid >> 6;
    if (lane == 0) { shf[wv] = s; shf[4 + wv] = q2; }
    __syncthreads();
    s = shf[0] + shf[1] + shf[2] + shf[3];
    q2 = shf[4] + shf[5] + shf[6] + shf[7];
    const float mu = s * (1.f / 2048.f);
    const float var = q2 * (1.f / 2048.f) - mu * mu;
    const float rs = rsqrtf(var + 1e-5f);
    f32x4 g0 = *(const f32x4*)(gamma + tid * 8);
    f32x4 g1 = *(const f32x4*)(gamma + tid * 8 + 4);
    f32x4 b0 = *(const f32x4*)(beta + tid * 8);
    f32x4 b1 = *(const f32x4*)(beta + tid * 8 + 4);
    bf16x8 o;
#pragma unroll
    for (int j = 0; j < 4; ++j) {
      o[j] = (bf16)((v0[j] - mu) * rs * g0[j] + b0[j]);
      o[4 + j] = (bf16)((v1[j] - mu) * rs * g1[j] + b1[j]);
    }
    *(bf16x8*)(xn + base) = o;
  } else if (blk < 16640) {
    transp64(Wq, wqT, 2048, 512, 0.125f, blk - 16384, shf);
  } else if (blk < 16896) {
    transp64(Wkv, wkvT, 1024, 1024, 1.f, blk - 16640, shf);
  } else if (blk < 17152) {
    transp64(Wout, woT, 512, 2048, 1.f, blk - 16896, shf);
  } else if (blk < 18176) {
    const int i = (blk - 17152) * 256 + tid;
    medb[i] = (bf16)media[i];
  } else if (blk < 18180) {
    int* part = (int*)shf;
    const int b = blk - 18176;
    int loc[16];
    int s = 0;
    const int base = b * 4096 + tid * 16;
#pragma unroll
    for (int j = 0; j < 16; ++j) {
      loc[j] = (mloc[base + j] != 0) ? 1 : 0;
      s += loc[j];
    }
    part[tid] = s;
    __syncthreads();
    for (int off = 1; off < 256; off <<= 1) {
      int v = (tid >= off) ? part[tid - off] : 0;
      __syncthreads();
      part[tid] += v;
      __syncthreads();
    }
    int c = (tid > 0) ? part[tid - 1] : 0;
#pragma unroll
    for (int j = 0; j < 16; ++j) {
      c += loc[j];
      int e = (c > 1 ? c : 1) << 3;  // *W=8
      endw[base + j] = e > 64 ? 64 : e;
    }
  } else {
    int* isbool = (int*)shf;
    if (tid == 0) *isbool = 0;
    __syncthreads();
    const unsigned char v = mraw[tid];
    if ((tid & 3) != 0 && v != 0) atomicOr(isbool, 1);
    __syncthreads();
    mk[tid] = (*isbool) ? (int)mraw[tid] : ((const int*)mraw)[tid];
  }
}

// ---------------------------------------------------------------------------
// Fused attention: block = (64 tokens, h, b); 4 waves, each owns 16 t-rows.
// ---------------------------------------------------------------------------
__global__ __launch_bounds__(256, 2) void attn_kernel(
    const bf16* __restrict__ q, const bf16* __restrict__ kv,
    const int* __restrict__ mk, const int* __restrict__ endw,
    bf16* __restrict__ ao) {
  __shared__ bf16 Ks[64 * 64], Vs[64 * 64], Ps[64 * 64];
  __shared__ int mks[64];
  const int tid = threadIdx.x, lane = tid & 63, w = tid >> 6;
  const int b = blockIdx.z, h = blockIdx.y, t0 = blockIdx.x * 64;

#pragma unroll
  for (int s0 = 0; s0 < 2; ++s0) {
    const int sidx = s0 * 256 + tid;
    const int r = sidx >> 3, sl = sidx & 7;
    *(bf16x8*)&Ks[r * 64 + ((sl ^ (r & 7)) << 3)] =
        *(const bf16x8*)&kv[(size_t)(b * 64 + r) * 1024 + h * 64 + sl * 8];
    bf16x8 vv =
        *(const bf16x8*)&kv[(size_t)(b * 64 + r) * 1024 + 512 + h * 64 + sl * 8];
#pragma unroll
    for (int j = 0; j < 8; ++j) {
      const int dh = sl * 8 + j;
      Vs[dh * 64 + ((((r >> 3) ^ (dh & 7)) << 3) | (r & 7))] = vv[j];
    }
  }
  if (tid < 64) mks[tid] = mk[b * 64 + tid];
  __syncthreads();

  const int g = lane >> 4, fr = lane & 15;
  bf16x8 aq[2];
#pragma unroll
  for (int kg = 0; kg < 2; ++kg)
    aq[kg] = *(const bf16x8*)&q[(size_t)(b * 4096 + t0 + w * 16 + fr) * 512 +
                                h * 64 + kg * 32 + g * 8];
  f32x4 sacc[4] = {};
#pragma unroll
  for (int kg = 0; kg < 2; ++kg)
#pragma unroll
    for (int ni = 0; ni < 4; ++ni) {
      const int r = ni * 16 + fr;
      bf16x8 bk = *(const bf16x8*)&Ks[r * 64 + (((kg * 4 + g) ^ (r & 7)) << 3)];
      sacc[ni] = __builtin_amdgcn_mfma_f32_16x16x32_bf16(aq[kg], bk, sacc[ni],
                                                         0, 0, 0);
    }

  const int4 ev4 = *(const int4*)&endw[b * 4096 + t0 + w * 16 + g * 4];
  const int ev[4] = {ev4.x, ev4.y, ev4.z, ev4.w};
  float p[4][4];
#pragma unroll
  for (int ni = 0; ni < 4; ++ni) {
    const int l = ni * 16 + fr;
    const bool mv = (mks[l] != 0);
#pragma unroll
    for (int rg = 0; rg < 4; ++rg)
      p[ni][rg] = (mv && (l < ev[rg])) ? sacc[ni][rg] : -FLT_MAX;
  }
#pragma unroll
  for (int rg = 0; rg < 4; ++rg) {
    float m = fmaxf(fmaxf(p[0][rg], p[1][rg]), fmaxf(p[2][rg], p[3][rg]));
    m = fmaxf(m, __shfl_xor(m, 1));
    m = fmaxf(m, __shfl_xor(m, 2));
    m = fmaxf(m, __shfl_xor(m, 4));
    m = fmaxf(m, __shfl_xor(m, 8));
    float sum = 0.f;
#pragma unroll
    for (int ni = 0; ni < 4; ++ni) {
      p[ni][rg] = __expf(p[ni][rg] - m);
      sum += p[ni][rg];
    }
    sum += __shfl_xor(sum, 1);
    sum += __shfl_xor(sum, 2);
    sum += __shfl_xor(sum, 4);
    sum += __shfl_xor(sum, 8);
    const float inv = 1.f / sum;
#pragma unroll
    for (int ni = 0; ni < 4; ++ni) p[ni][rg] *= inv;
  }
#pragma unroll
  for (int ni = 0; ni < 4; ++ni) {
    const int l = ni * 16 + fr;
#pragma unroll
    for (int rg = 0; rg < 4; ++rg) {
      const int tr = w * 16 + g * 4 + rg;
      Ps[tr * 64 + ((((l >> 3) ^ (tr & 7)) << 3) | (l & 7))] = (bf16)p[ni][rg];
    }
  }
  __syncthreads();

  bf16x8 pa[2];
#pragma unroll
  for (int kg = 0; kg < 2; ++kg) {
    const int r = w * 16 + fr;
    pa[kg] = *(const bf16x8*)&Ps[r * 64 + (((kg * 4 + g) ^ (r & 7)) << 3)];
  }
  f32x4 oacc[4] = {};
#pragma unroll
  for (int kg = 0; kg < 2; ++kg)
#pragma unroll
    for (int ni = 0; ni < 4; ++ni) {
      const int r = ni * 16 + fr;
      bf16x8 bv = *(const bf16x8*)&Vs[r * 64 + (((kg * 4 + g) ^ (r & 7)) << 3)];
      oacc[ni] = __builtin_amdgcn_mfma_f32_16x16x32_bf16(pa[kg], bv, oacc[ni],
                                                         0, 0, 0);
    }
#pragma unroll
  for (int ni = 0; ni < 4; ++ni)
#pragma unroll
    for (int rg = 0; rg < 4; ++rg)
      ao[(size_t)(b * 4096 + t0 + w * 16 + g * 4 + rg) * 512 + h * 64 +
         ni * 16 + fr] = (bf16)oacc[ni][rg];
}

// ---------------------------------------------------------------------------
extern "C" void kernel_launch(void* const* d_in, const int* in_sizes, int n_in,
                              void* d_out, int out_size, void* d_ws,
                              size_t ws_size, hipStream_t stream) {
  const float* x = (const float*)d_in[0];
  const float* media = (const float*)d_in[1];
  const unsigned char* mraw = (const unsigned char*)d_in[2];
  const int* mloc = (const int*)d_in[3];
  const float* Wq = (const float*)d_in[4];
  const float* Wkv = (const float*)d_in[5];
  const float* Wout = (const float*)d_in[6];
  const float* gamma = (const float*)d_in[7];
  const float* beta = (const float*)d_in[8];
  float* out = (float*)d_out;

  // xn (bf16, 67MB) lives in d_out scratch; dead before final GEMM overwrites.
  bf16* xn = (bf16*)d_out;

  char* ws = (char*)d_ws;
  size_t off = 0;
  auto carve = [&](size_t bytes) {
    void* p = ws + off;
    off += (bytes + 255) & ~(size_t)255;
    return p;
  };
  bf16* qb = (bf16*)carve((size_t)16384 * 512 * 2);
  bf16* aob = (bf16*)carve((size_t)16384 * 512 * 2);
  bf16* kvb = (bf16*)carve((size_t)256 * 1024 * 2);
  bf16* wqT = (bf16*)carve((size_t)512 * 2048 * 2);
  bf16* wkvT = (bf16*)carve((size_t)1024 * 1024 * 2);
  bf16* woT = (bf16*)carve((size_t)2048 * 512 * 2);
  bf16* medb = (bf16*)carve((size_t)256 * 1024 * 2);
  int* endw = (int*)carve((size_t)4 * 4096 * 4);
  int* mk = (int*)carve(256 * 4);
  (void)ws_size;
  (void)in_sizes;
  (void)n_in;
  (void)out_size;

  // one fused prep pass (LN, 3 weight transposes, media cast, cumsum, mask)
  prep_all<<<18181, 256, 0, stream>>>(x, gamma, beta, xn, Wq, wqT, Wkv, wkvT,
                                      Wout, woT, media, medb, mloc, endw, mraw,
                                      mk);

  // KV projection (small)
  gemm_bt<1><<<dim3(8, 2), 256, 0, stream>>>(medb, wkvT, kvb, 256, 1024, 1024);

  // Q projection: BM=256, BN=128 (4Mx2N waves) -> grid 4x64 = 256 blocks
  gemm_8ph<1, 128, 4, 2><<<dim3(4, 64), 512, 0, stream>>>(xn, wqT, qb, 16384,
                                                          512, 2048);

  // attention (V transposed on the fly from kvb)
  attn_kernel<<<dim3(64, 8, 4), 256, 0, stream>>>(qb, kvb, mk, endw, aob);

  // output projection: BM=256, BN=256 (2Mx4N waves) -> grid 8x64 = 512 blocks
  gemm_8ph<0, 256, 2, 4><<<dim3(8, 64), 512, 0, stream>>>(aob, woT, out, 16384,
                                                          2048, 512);
}

// Round 6
// 184.800 us; speedup vs baseline: 1.0946x; 1.0946x over previous
//
#include <hip/hip_runtime.h>
#include <float.h>

typedef __bf16 bf16;
typedef __bf16 bf16x8 __attribute__((ext_vector_type(8)));
typedef float f32x4 __attribute__((ext_vector_type(4)));
typedef float f32x16 __attribute__((ext_vector_type(16)));

#define GAS __attribute__((address_space(1)))
#define LAS __attribute__((address_space(3)))

__device__ __forceinline__ void gload_lds16(const void* g, void* l) {
  __builtin_amdgcn_global_load_lds((const GAS unsigned int*)g, (LAS unsigned int*)l, 16, 0, 0);
}

// ---------------------------------------------------------------------------
// Big GEMM: C[M,N] = A[M,K] @ Bt[N,K]^T, bf16 row-major inputs.
// BM=256, BN=128, BK=64. 8 waves (2M x 4N), per-wave 128x32.
// MFMA 32x32x16 (the faster pipe: 2495 vs 2176 TF ubench; half the
// instruction count of 16x16x32 for the same FLOPs).
// Ring-3 LDS (144 KB). ONE s_barrier + ONE counted vmcnt(6) per K-tile;
// prefetch distance = 2 K-tiles. 16B-slot XOR swizzle by (row&7); global
// source pre-swizzled so global_load_lds' linear dest yields swizzled LDS.
// (Identical staging/sync structure to the R4 baseline; only the compute
// fragments + epilogue changed to 32x32.)
// ---------------------------------------------------------------------------
template <int OUT_BF16>
__global__ __launch_bounds__(512, 2) void gemm_big(
    const bf16* __restrict__ A, const bf16* __restrict__ Bt,
    void* __restrict__ Cv, int M, int N, int K) {
  __shared__ __align__(16) bf16 Abuf[3][256 * 64];
  __shared__ __align__(16) bf16 Bbuf[3][128 * 64];
  const int tid = threadIdx.x, lane = tid & 63;
  const int w = tid >> 6, wr = w >> 2, wc = w & 3;
  const int l31 = lane & 31, hi = lane >> 5;

  // bijective XCD-chunked swizzle (m204)
  const int gx = gridDim.x;
  const int nwg = gx * gridDim.y;
  int lid = blockIdx.y * gx + blockIdx.x;
  {
    const int qq = nwg >> 3, rr = nwg & 7;
    const int xcd = lid & 7, pos = lid >> 3;
    lid = (xcd < rr ? xcd * (qq + 1) : rr * (qq + 1) + (xcd - rr) * qq) + pos;
  }
  const int bx = lid % gx, by = lid / gx;
  const size_t m0 = (size_t)by * 256, n0 = (size_t)bx * 128;

  const int nt = K >> 6;
  const int srow = tid >> 3;  // 0..63 (row within 64-row staging step)
  const int sslot = tid & 7;  // 16B slot within 128B row

  f32x16 acc[4] = {};

  auto stage = [&](int t) {
    const int s = t % 3;
    const int kt = t << 6;
#pragma unroll
    for (int c = 0; c < 4; ++c) {  // A: 256 rows in 4 steps of 64
      const int r = c * 64 + srow;
      gload_lds16(A + (m0 + r) * (size_t)K + kt + ((sslot ^ (r & 7)) << 3),
                  &Abuf[s][c * 4096 + w * 512]);
    }
#pragma unroll
    for (int c = 0; c < 2; ++c) {  // B: 128 rows in 2 steps of 64
      const int r = c * 64 + srow;
      gload_lds16(Bt + (n0 + r) * (size_t)K + kt + ((sslot ^ (r & 7)) << 3),
                  &Bbuf[s][c * 4096 + w * 512]);
    }
  };

  // 32x32x16 fragments: lane -> row = l31, k = hi*8 + j (16B contiguous)
  auto rdA = [&](int s, int mi, int ks) {
    const int r = wr * 128 + mi * 32 + l31;
    return *(const bf16x8*)&Abuf[s][r * 64 + ((((ks << 1) | hi) ^ (r & 7)) << 3)];
  };
  auto rdB = [&](int s, int ks) {
    const int r = wc * 32 + l31;
    return *(const bf16x8*)&Bbuf[s][r * 64 + ((((ks << 1) | hi) ^ (r & 7)) << 3)];
  };

  auto compute = [&](int t) {
    const int s = t % 3;
    bf16x8 bv[4];
#pragma unroll
    for (int ks = 0; ks < 4; ++ks) bv[ks] = rdB(s, ks);
    __builtin_amdgcn_s_setprio(1);
#pragma unroll
    for (int ks = 0; ks < 4; ++ks)
#pragma unroll
      for (int mi = 0; mi < 4; ++mi) {
        const bf16x8 av = rdA(s, mi, ks);
        acc[mi] = __builtin_amdgcn_mfma_f32_32x32x16_bf16(av, bv[ks], acc[mi],
                                                          0, 0, 0);
      }
    __builtin_amdgcn_s_setprio(0);
  };

  // prologue: stage K-tiles 0 and 1 (12 loads/thread in flight)
  stage(0);
  stage(1);

  for (int t = 0; t < nt - 1; ++t) {
    __builtin_amdgcn_sched_barrier(0);
    asm volatile("s_waitcnt vmcnt(6)" ::: "memory");  // tile t's loads landed
    __builtin_amdgcn_s_barrier();  // all waves: t visible, t-1 reads done
    __builtin_amdgcn_sched_barrier(0);
    if (t + 2 < nt) stage(t + 2);  // overwrite slot (t-1)%3
    compute(t);
  }
  __builtin_amdgcn_sched_barrier(0);
  asm volatile("s_waitcnt vmcnt(0)" ::: "memory");
  __builtin_amdgcn_s_barrier();
  __builtin_amdgcn_sched_barrier(0);
  compute(nt - 1);

  // C/D layout (m74/m101): col = l31, row = (rg&3) + 8*(rg>>2) + 4*hi
#pragma unroll
  for (int mi = 0; mi < 4; ++mi)
#pragma unroll
    for (int rg = 0; rg < 16; ++rg) {
      const size_t row =
          m0 + wr * 128 + mi * 32 + (rg & 3) + ((rg >> 2) << 3) + (hi << 2);
      const size_t col = n0 + wc * 32 + l31;
      if (OUT_BF16)
        ((bf16*)Cv)[row * (size_t)N + col] = (bf16)acc[mi][rg];
      else
        ((float*)Cv)[row * (size_t)N + col] = acc[mi][rg];
    }
}

// ---------------------------------------------------------------------------
// Small GEMM (KV projection): m97-style 128x128 tile, BK=32.
// ---------------------------------------------------------------------------
template <int OUT_BF16>
__global__ __launch_bounds__(256, 2) void gemm_bt(
    const bf16* __restrict__ A, const bf16* __restrict__ Bt,
    void* __restrict__ Cv, int M, int N, int K) {
  __shared__ bf16 As[128 * 32];
  __shared__ bf16 Bs[128 * 32];
  const int tid = threadIdx.x;
  const int lane = tid & 63, w = tid >> 6;
  const int wr = w >> 1, wc = w & 1;

  const int gx = gridDim.x;
  const int nwg = gx * gridDim.y;
  int lid = blockIdx.y * gx + blockIdx.x;
  {
    const int qq = nwg >> 3, rr = nwg & 7;
    const int xcd = lid & 7, pos = lid >> 3;
    lid = (xcd < rr ? xcd * (qq + 1) : rr * (qq + 1) + (xcd - rr) * qq) + pos;
  }
  const int bx = lid % gx, by = lid / gx;
  const size_t m0 = (size_t)by * 128, n0 = (size_t)bx * 128;

  const int srow = lane >> 2, sslot = lane & 3;
  const int g = lane >> 4, fr = lane & 15;

  f32x4 acc[4][4] = {};

  for (int kt = 0; kt < K; kt += 32) {
    __syncthreads();
#pragma unroll
    for (int j = 0; j < 2; ++j) {
      const int c = 2 * w + j;
      const int r = c * 16 + srow;
      const int ks = (sslot ^ (r & 3)) << 3;
      gload_lds16(A + (m0 + r) * K + kt + ks, &As[c * 512]);
      gload_lds16(Bt + (n0 + r) * K + kt + ks, &Bs[c * 512]);
    }
    __syncthreads();
    bf16x8 av[4], bv[4];
#pragma unroll
    for (int mi = 0; mi < 4; ++mi) {
      const int r = wr * 64 + mi * 16 + fr;
      av[mi] = *(const bf16x8*)&As[r * 32 + ((g ^ (r & 3)) << 3)];
    }
#pragma unroll
    for (int ni = 0; ni < 4; ++ni) {
      const int r = wc * 64 + ni * 16 + fr;
      bv[ni] = *(const bf16x8*)&Bs[r * 32 + ((g ^ (r & 3)) << 3)];
    }
#pragma unroll
    for (int mi = 0; mi < 4; ++mi)
#pragma unroll
      for (int ni = 0; ni < 4; ++ni)
        acc[mi][ni] = __builtin_amdgcn_mfma_f32_16x16x32_bf16(
            av[mi], bv[ni], acc[mi][ni], 0, 0, 0);
  }

#pragma unroll
  for (int mi = 0; mi < 4; ++mi)
#pragma unroll
    for (int ni = 0; ni < 4; ++ni)
#pragma unroll
      for (int rg = 0; rg < 4; ++rg) {
        const size_t row = m0 + wr * 64 + mi * 16 + g * 4 + rg;
        const size_t col = n0 + wc * 64 + ni * 16 + fr;
        if (OUT_BF16)
          ((bf16*)Cv)[row * (size_t)N + col] = (bf16)acc[mi][ni][rg];
        else
          ((float*)Cv)[row * (size_t)N + col] = acc[mi][ni][rg];
      }
}

// ---------------------------------------------------------------------------
// Coalesced 64x64 LDS-tiled transpose: dst[C][R] = src[R][C] * scale (bf16)
// ---------------------------------------------------------------------------
__device__ __forceinline__ void transp64(const float* __restrict__ src,
                                         bf16* __restrict__ dst, int R, int C,
                                         float scale, int tile, float* lds) {
  const int tilesC = C >> 6;
  const int tr = tile / tilesC, tc = tile % tilesC;
  const int r0 = tr << 6, c0 = tc << 6;
  const int tid = threadIdx.x;
  const int lr = tid >> 6, lc = tid & 63;
#pragma unroll
  for (int j = 0; j < 16; ++j) {
    const int r = j * 4 + lr;
    lds[r * 65 + lc] = src[(size_t)(r0 + r) * C + c0 + lc];
  }
  __syncthreads();
#pragma unroll
  for (int j = 0; j < 16; ++j) {
    const int rr = j * 4 + lr;  // dst row = src col
    dst[(size_t)(c0 + rr) * R + r0 + lc] = (bf16)(lds[lc * 65 + rr] * scale);
  }
}

// ---------------------------------------------------------------------------
// Mega prep kernel: one launch, block-range partitioned.
// ---------------------------------------------------------------------------
__global__ __launch_bounds__(256) void prep_all(
    const float* __restrict__ x, const float* __restrict__ gamma,
    const float* __restrict__ beta, bf16* __restrict__ xn,
    const float* __restrict__ Wq, bf16* __restrict__ wqT,
    const float* __restrict__ Wkv, bf16* __restrict__ wkvT,
    const float* __restrict__ Wout, bf16* __restrict__ woT,
    const float* __restrict__ media, bf16* __restrict__ medb,
    const int* __restrict__ mloc, int* __restrict__ endw,
    const unsigned char* __restrict__ mraw, int* __restrict__ mk) {
  __shared__ float shf[64 * 65];
  const int blk = blockIdx.x, tid = threadIdx.x;

  if (blk < 16384) {
    const size_t base = (size_t)blk * 2048 + tid * 8;
    f32x4 v0 = *(const f32x4*)(x + base);
    f32x4 v1 = *(const f32x4*)(x + base + 4);
    float s = 0.f, q2 = 0.f;
#pragma unroll
    for (int j = 0; j < 4; ++j) {
      s += v0[j] + v1[j];
      q2 += v0[j] * v0[j] + v1[j] * v1[j];
    }
    for (int off = 32; off > 0; off >>= 1) {
      s += __shfl_down(s, off);
      q2 += __shfl_down(q2, off);
    }
    const int lane = tid & 63, wv = tid >> 6;
    if (lane == 0) { shf[wv] = s; shf[4 + wv] = q2; }
    __syncthreads();
    s = shf[0] + shf[1] + shf[2] + shf[3];
    q2 = shf[4] + shf[5] + shf[6] + shf[7];
    const float mu = s * (1.f / 2048.f);
    const float var = q2 * (1.f / 2048.f) - mu * mu;
    const float rs = rsqrtf(var + 1e-5f);
    f32x4 g0 = *(const f32x4*)(gamma + tid * 8);
    f32x4 g1 = *(const f32x4*)(gamma + tid * 8 + 4);
    f32x4 b0 = *(const f32x4*)(beta + tid * 8);
    f32x4 b1 = *(const f32x4*)(beta + tid * 8 + 4);
    bf16x8 o;
#pragma unroll
    for (int j = 0; j < 4; ++j) {
      o[j] = (bf16)((v0[j] - mu) * rs * g0[j] + b0[j]);
      o[4 + j] = (bf16)((v1[j] - mu) * rs * g1[j] + b1[j]);
    }
    *(bf16x8*)(xn + base) = o;
  } else if (blk < 16640) {
    transp64(Wq, wqT, 2048, 512, 0.125f, blk - 16384, shf);
  } else if (blk < 16896) {
    transp64(Wkv, wkvT, 1024, 1024, 1.f, blk - 16640, shf);
  } else if (blk < 17152) {
    transp64(Wout, woT, 512, 2048, 1.f, blk - 16896, shf);
  } else if (blk < 18176) {
    const int i = (blk - 17152) * 256 + tid;
    medb[i] = (bf16)media[i];
  } else if (blk < 18180) {
    int* part = (int*)shf;
    const int b = blk - 18176;
    int loc[16];
    int s = 0;
    const int base = b * 4096 + tid * 16;
#pragma unroll
    for (int j = 0; j < 16; ++j) {
      loc[j] = (mloc[base + j] != 0) ? 1 : 0;
      s += loc[j];
    }
    part[tid] = s;
    __syncthreads();
    for (int off = 1; off < 256; off <<= 1) {
      int v = (tid >= off) ? part[tid - off] : 0;
      __syncthreads();
      part[tid] += v;
      __syncthreads();
    }
    int c = (tid > 0) ? part[tid - 1] : 0;
#pragma unroll
    for (int j = 0; j < 16; ++j) {
      c += loc[j];
      int e = (c > 1 ? c : 1) << 3;  // *W=8
      endw[base + j] = e > 64 ? 64 : e;
    }
  } else {
    int* isbool = (int*)shf;
    if (tid == 0) *isbool = 0;
    __syncthreads();
    const unsigned char v = mraw[tid];
    if ((tid & 3) != 0 && v != 0) atomicOr(isbool, 1);
    __syncthreads();
    mk[tid] = (*isbool) ? (int)mraw[tid] : ((const int*)mraw)[tid];
  }
}

// ---------------------------------------------------------------------------
// Fused attention: block = (64 tokens, h, b); 4 waves, each owns 16 t-rows.
// ---------------------------------------------------------------------------
__global__ __launch_bounds__(256, 2) void attn_kernel(
    const bf16* __restrict__ q, const bf16* __restrict__ kv,
    const int* __restrict__ mk, const int* __restrict__ endw,
    bf16* __restrict__ ao) {
  __shared__ bf16 Ks[64 * 64], Vs[64 * 64], Ps[64 * 64];
  __shared__ int mks[64];
  const int tid = threadIdx.x, lane = tid & 63, w = tid >> 6;
  const int b = blockIdx.z, h = blockIdx.y, t0 = blockIdx.x * 64;

#pragma unroll
  for (int s0 = 0; s0 < 2; ++s0) {
    const int sidx = s0 * 256 + tid;
    const int r = sidx >> 3, sl = sidx & 7;
    *(bf16x8*)&Ks[r * 64 + ((sl ^ (r & 7)) << 3)] =
        *(const bf16x8*)&kv[(size_t)(b * 64 + r) * 1024 + h * 64 + sl * 8];
    bf16x8 vv =
        *(const bf16x8*)&kv[(size_t)(b * 64 + r) * 1024 + 512 + h * 64 + sl * 8];
#pragma unroll
    for (int j = 0; j < 8; ++j) {
      const int dh = sl * 8 + j;
      Vs[dh * 64 + ((((r >> 3) ^ (dh & 7)) << 3) | (r & 7))] = vv[j];
    }
  }
  if (tid < 64) mks[tid] = mk[b * 64 + tid];
  __syncthreads();

  const int g = lane >> 4, fr = lane & 15;
  bf16x8 aq[2];
#pragma unroll
  for (int kg = 0; kg < 2; ++kg)
    aq[kg] = *(const bf16x8*)&q[(size_t)(b * 4096 + t0 + w * 16 + fr) * 512 +
                                h * 64 + kg * 32 + g * 8];
  f32x4 sacc[4] = {};
#pragma unroll
  for (int kg = 0; kg < 2; ++kg)
#pragma unroll
    for (int ni = 0; ni < 4; ++ni) {
      const int r = ni * 16 + fr;
      bf16x8 bk = *(const bf16x8*)&Ks[r * 64 + (((kg * 4 + g) ^ (r & 7)) << 3)];
      sacc[ni] = __builtin_amdgcn_mfma_f32_16x16x32_bf16(aq[kg], bk, sacc[ni],
                                                         0, 0, 0);
    }

  const int4 ev4 = *(const int4*)&endw[b * 4096 + t0 + w * 16 + g * 4];
  const int ev[4] = {ev4.x, ev4.y, ev4.z, ev4.w};
  float p[4][4];
#pragma unroll
  for (int ni = 0; ni < 4; ++ni) {
    const int l = ni * 16 + fr;
    const bool mv = (mks[l] != 0);
#pragma unroll
    for (int rg = 0; rg < 4; ++rg)
      p[ni][rg] = (mv && (l < ev[rg])) ? sacc[ni][rg] : -FLT_MAX;
  }
#pragma unroll
  for (int rg = 0; rg < 4; ++rg) {
    float m = fmaxf(fmaxf(p[0][rg], p[1][rg]), fmaxf(p[2][rg], p[3][rg]));
    m = fmaxf(m, __shfl_xor(m, 1));
    m = fmaxf(m, __shfl_xor(m, 2));
    m = fmaxf(m, __shfl_xor(m, 4));
    m = fmaxf(m, __shfl_xor(m, 8));
    float sum = 0.f;
#pragma unroll
    for (int ni = 0; ni < 4; ++ni) {
      p[ni][rg] = __expf(p[ni][rg] - m);
      sum += p[ni][rg];
    }
    sum += __shfl_xor(sum, 1);
    sum += __shfl_xor(sum, 2);
    sum += __shfl_xor(sum, 4);
    sum += __shfl_xor(sum, 8);
    const float inv = 1.f / sum;
#pragma unroll
    for (int ni = 0; ni < 4; ++ni) p[ni][rg] *= inv;
  }
#pragma unroll
  for (int ni = 0; ni < 4; ++ni) {
    const int l = ni * 16 + fr;
#pragma unroll
    for (int rg = 0; rg < 4; ++rg) {
      const int tr = w * 16 + g * 4 + rg;
      Ps[tr * 64 + ((((l >> 3) ^ (tr & 7)) << 3) | (l & 7))] = (bf16)p[ni][rg];
    }
  }
  __syncthreads();

  bf16x8 pa[2];
#pragma unroll
  for (int kg = 0; kg < 2; ++kg) {
    const int r = w * 16 + fr;
    pa[kg] = *(const bf16x8*)&Ps[r * 64 + (((kg * 4 + g) ^ (r & 7)) << 3)];
  }
  f32x4 oacc[4] = {};
#pragma unroll
  for (int kg = 0; kg < 2; ++kg)
#pragma unroll
    for (int ni = 0; ni < 4; ++ni) {
      const int r = ni * 16 + fr;
      bf16x8 bv = *(const bf16x8*)&Vs[r * 64 + (((kg * 4 + g) ^ (r & 7)) << 3)];
      oacc[ni] = __builtin_amdgcn_mfma_f32_16x16x32_bf16(pa[kg], bv, oacc[ni],
                                                         0, 0, 0);
    }
#pragma unroll
  for (int ni = 0; ni < 4; ++ni)
#pragma unroll
    for (int rg = 0; rg < 4; ++rg)
      ao[(size_t)(b * 4096 + t0 + w * 16 + g * 4 + rg) * 512 + h * 64 +
         ni * 16 + fr] = (bf16)oacc[ni][rg];
}

// ---------------------------------------------------------------------------
extern "C" void kernel_launch(void* const* d_in, const int* in_sizes, int n_in,
                              void* d_out, int out_size, void* d_ws,
                              size_t ws_size, hipStream_t stream) {
  const float* x = (const float*)d_in[0];
  const float* media = (const float*)d_in[1];
  const unsigned char* mraw = (const unsigned char*)d_in[2];
  const int* mloc = (const int*)d_in[3];
  const float* Wq = (const float*)d_in[4];
  const float* Wkv = (const float*)d_in[5];
  const float* Wout = (const float*)d_in[6];
  const float* gamma = (const float*)d_in[7];
  const float* beta = (const float*)d_in[8];
  float* out = (float*)d_out;

  // xn (bf16, 67MB) lives in d_out scratch; dead before final GEMM overwrites.
  bf16* xn = (bf16*)d_out;

  char* ws = (char*)d_ws;
  size_t off = 0;
  auto carve = [&](size_t bytes) {
    void* p = ws + off;
    off += (bytes + 255) & ~(size_t)255;
    return p;
  };
  bf16* qb = (bf16*)carve((size_t)16384 * 512 * 2);
  bf16* aob = (bf16*)carve((size_t)16384 * 512 * 2);
  bf16* kvb = (bf16*)carve((size_t)256 * 1024 * 2);
  bf16* wqT = (bf16*)carve((size_t)512 * 2048 * 2);
  bf16* wkvT = (bf16*)carve((size_t)1024 * 1024 * 2);
  bf16* woT = (bf16*)carve((size_t)2048 * 512 * 2);
  bf16* medb = (bf16*)carve((size_t)256 * 1024 * 2);
  int* endw = (int*)carve((size_t)4 * 4096 * 4);
  int* mk = (int*)carve(256 * 4);
  (void)ws_size;
  (void)in_sizes;
  (void)n_in;
  (void)out_size;

  // one fused prep pass (LN, 3 weight transposes, media cast, cumsum, mask)
  prep_all<<<18181, 256, 0, stream>>>(x, gamma, beta, xn, Wq, wqT, Wkv, wkvT,
                                      Wout, woT, media, medb, mloc, endw, mraw,
                                      mk);

  // KV projection (small)
  gemm_bt<1><<<dim3(8, 2), 256, 0, stream>>>(medb, wkvT, kvb, 256, 1024, 1024);

  // Q projection: BM=256, BN=128, BK=64 -> grid 4 x 64 = 256 blocks
  gemm_big<1><<<dim3(4, 64), 512, 0, stream>>>(xn, wqT, qb, 16384, 512, 2048);

  // attention (V transposed on the fly from kvb)
  attn_kernel<<<dim3(64, 8, 4), 256, 0, stream>>>(qb, kvb, mk, endw, aob);

  // output projection (f32 out): grid 16 x 64 = 1024 blocks
  gemm_big<0><<<dim3(16, 64), 512, 0, stream>>>(aob, woT, out, 16384, 2048,
                                                512);
}

// Round 7
// 177.703 us; speedup vs baseline: 1.1384x; 1.0399x over previous
//
#include <hip/hip_runtime.h>
#include <float.h>

typedef __bf16 bf16;
typedef __bf16 bf16x8 __attribute__((ext_vector_type(8)));
typedef float f32x4 __attribute__((ext_vector_type(4)));
typedef float f32x16 __attribute__((ext_vector_type(16)));

#define GAS __attribute__((address_space(1)))
#define LAS __attribute__((address_space(3)))

__device__ __forceinline__ void gload_lds16(const void* g, void* l) {
  __builtin_amdgcn_global_load_lds((const GAS unsigned int*)g, (LAS unsigned int*)l, 16, 0, 0);
}

// ---------------------------------------------------------------------------
// FUSED Q-projection GEMM + attention.
// GEMM part: qacc[256 x 128] = xn[256 x 2048] @ wqT[128 x 2048]^T per block.
//   8 waves as 4M x 2N: wave tile 64 rows x 64 cols (= 1 head).
//   BK=64, ring-3 LDS (144 KB), ONE s_barrier + ONE vmcnt(6) per K-tile
//   (identical ledger to the R4 baseline). 16 ds_read_b128 : 32 MFMA per
//   wave per K-tile (ratio 0.5 vs 0.625 before -> less LDS-read-bound).
// Attention part (in-epilogue): block covers 256 tokens x 2 heads of batch
//   b = m0>>12; wave (wr,wc) owns 64 tokens x head wc. Q-acc -> wave-private
//   LDS (bf16, XOR-swizzled); K staged via global_load_lds, V reg-transposed
//   into the dead ring slots; QK^T -> mask -> softmax -> PV; write aob.
// ---------------------------------------------------------------------------
__global__ __launch_bounds__(512, 2) void qattn(
    const bf16* __restrict__ xn, const bf16* __restrict__ wqT,
    const bf16* __restrict__ kvb, const int* __restrict__ mk,
    const int* __restrict__ endw, bf16* __restrict__ aob) {
  constexpr int K = 2048;
  __shared__ __align__(16) bf16 Abuf[3][256 * 64];  // 96 KB
  __shared__ __align__(16) bf16 Bbuf[3][128 * 64];  // 48 KB
  const int tid = threadIdx.x, lane = tid & 63;
  const int w = tid >> 6, wr = w >> 1, wc = w & 1;
  const int g = lane >> 4, fr = lane & 15;

  // bijective XCD-chunked swizzle (m204)
  const int gx = gridDim.x;
  const int nwg = gx * gridDim.y;
  int lid = blockIdx.y * gx + blockIdx.x;
  {
    const int qq = nwg >> 3, rr = nwg & 7;
    const int xcd = lid & 7, pos = lid >> 3;
    lid = (xcd < rr ? xcd * (qq + 1) : rr * (qq + 1) + (xcd - rr) * qq) + pos;
  }
  const int bx = lid % gx, by = lid / gx;
  const size_t m0 = (size_t)by * 256;
  const int n0 = bx * 128;  // 2 heads: 2*bx, 2*bx+1

  const int nt = K >> 6;  // 32
  const int srow = tid >> 3, sslot = tid & 7;

  f32x4 acc[4][4] = {};

  auto stage = [&](int t) {
    const int s = t % 3;
    const int kt = t << 6;
#pragma unroll
    for (int c = 0; c < 4; ++c) {
      const int r = c * 64 + srow;
      gload_lds16(xn + (m0 + r) * (size_t)K + kt + ((sslot ^ (r & 7)) << 3),
                  &Abuf[s][c * 4096 + w * 512]);
    }
#pragma unroll
    for (int c = 0; c < 2; ++c) {
      const int r = c * 64 + srow;
      gload_lds16(wqT + (size_t)(n0 + r) * K + kt + ((sslot ^ (r & 7)) << 3),
                  &Bbuf[s][c * 4096 + w * 512]);
    }
  };
  auto rdA = [&](int s, int mi, int ks) {
    const int r = wr * 64 + mi * 16 + fr;
    return *(const bf16x8*)&Abuf[s][r * 64 + ((((ks << 2) | g) ^ (r & 7)) << 3)];
  };
  auto rdB = [&](int s, int ni, int ks) {
    const int r = wc * 64 + ni * 16 + fr;
    return *(const bf16x8*)&Bbuf[s][r * 64 + ((((ks << 2) | g) ^ (r & 7)) << 3)];
  };
  auto compute = [&](int t) {
    const int s = t % 3;
    bf16x8 bv[4][2];
#pragma unroll
    for (int ni = 0; ni < 4; ++ni)
#pragma unroll
      for (int ks = 0; ks < 2; ++ks) bv[ni][ks] = rdB(s, ni, ks);
    __builtin_amdgcn_s_setprio(1);
#pragma unroll
    for (int mi = 0; mi < 4; ++mi)
#pragma unroll
      for (int ks = 0; ks < 2; ++ks) {
        const bf16x8 av = rdA(s, mi, ks);
#pragma unroll
        for (int ni = 0; ni < 4; ++ni)
          acc[mi][ni] = __builtin_amdgcn_mfma_f32_16x16x32_bf16(
              av, bv[ni][ks], acc[mi][ni], 0, 0, 0);
      }
    __builtin_amdgcn_s_setprio(0);
  };

  stage(0);
  stage(1);
  for (int t = 0; t < nt - 1; ++t) {
    __builtin_amdgcn_sched_barrier(0);
    asm volatile("s_waitcnt vmcnt(6)" ::: "memory");
    __builtin_amdgcn_s_barrier();
    __builtin_amdgcn_sched_barrier(0);
    if (t + 2 < nt) stage(t + 2);
    compute(t);
  }
  __builtin_amdgcn_sched_barrier(0);
  asm volatile("s_waitcnt vmcnt(0)" ::: "memory");
  __builtin_amdgcn_s_barrier();
  __builtin_amdgcn_sched_barrier(0);
  compute(nt - 1);

  // ======== attention epilogue ========
  __builtin_amdgcn_s_barrier();  // all waves done with ring buffers
  __builtin_amdgcn_sched_barrier(0);

  const int b = (int)(m0 >> 12);
  bf16* QP = &Abuf[0][0] + w * 4096;  // wave-private [64 rows][128B]
  bf16* Klds = &Bbuf[0][0];           // [2 heads][64 l][128B]
  bf16* Vlds = &Bbuf[1][0];           // [2 heads][64 dh][128B]

  // Q acc -> QP (bf16, swizzled rows of 128B)
#pragma unroll
  for (int mi = 0; mi < 4; ++mi)
#pragma unroll
    for (int ni = 0; ni < 4; ++ni)
#pragma unroll
      for (int rg = 0; rg < 4; ++rg) {
        const int row = mi * 16 + g * 4 + rg, col = ni * 16 + fr;
        QP[row * 64 + (((col >> 3) ^ (row & 7)) << 3) + (col & 7)] =
            (bf16)acc[mi][ni][rg];
      }

  // K stage via global_load_lds (linear dest = base + lane*16)
#pragma unroll
  for (int j = 0; j < 2; ++j) {
    const int idx = j * 512 + tid;
    const int head = idx >> 9, l = (idx >> 3) & 63, sl = idx & 7;
    gload_lds16(kvb + (size_t)(b * 64 + l) * 1024 + (2 * bx + head) * 64 +
                    ((sl ^ (l & 7)) << 3),
                Klds + (j * 512 + w * 64) * 8);
  }
  // V stage with in-register transpose
#pragma unroll
  for (int j = 0; j < 2; ++j) {
    const int idx = j * 512 + tid;
    const int head = idx >> 9, l = (idx >> 3) & 63, sg = idx & 7;
    bf16x8 vv = *(const bf16x8*)&kvb[(size_t)(b * 64 + l) * 1024 + 512 +
                                     (2 * bx + head) * 64 + sg * 8];
#pragma unroll
    for (int e = 0; e < 8; ++e) {
      const int dh = sg * 8 + e;
      Vlds[head * 4096 + dh * 64 + (((l >> 3) ^ (dh & 7)) << 3) + (l & 7)] =
          vv[e];
    }
  }
  asm volatile("s_waitcnt vmcnt(0)" ::: "memory");
  __syncthreads();

  // S = Q @ K^T   (rows t, cols l)
  f32x4 sacc[4][4] = {};
#pragma unroll
  for (int ks = 0; ks < 2; ++ks) {
    bf16x8 aq[4], bk[4];
#pragma unroll
    for (int mi = 0; mi < 4; ++mi) {
      const int r = mi * 16 + fr;
      aq[mi] = *(const bf16x8*)&QP[r * 64 + ((((ks << 2) | g) ^ (r & 7)) << 3)];
    }
#pragma unroll
    for (int ni = 0; ni < 4; ++ni) {
      const int l = ni * 16 + fr;
      bk[ni] = *(const bf16x8*)&Klds[wc * 4096 + l * 64 +
                                     ((((ks << 2) | g) ^ (l & 7)) << 3)];
    }
#pragma unroll
    for (int mi = 0; mi < 4; ++mi)
#pragma unroll
      for (int ni = 0; ni < 4; ++ni)
        sacc[mi][ni] = __builtin_amdgcn_mfma_f32_16x16x32_bf16(
            aq[mi], bk[ni], sacc[mi][ni], 0, 0, 0);
  }

  // mask + softmax per 16-row group, then P -> QP (overwrites dead Q)
#pragma unroll
  for (int mi = 0; mi < 4; ++mi) {
    const int4 ev4 = *(const int4*)&endw[m0 + wr * 64 + mi * 16 + g * 4];
    const int ev[4] = {ev4.x, ev4.y, ev4.z, ev4.w};
    float p[4][4];
#pragma unroll
    for (int ni = 0; ni < 4; ++ni) {
      const int l = ni * 16 + fr;
      const bool mv = (mk[b * 64 + l] != 0);
#pragma unroll
      for (int rg = 0; rg < 4; ++rg)
        p[ni][rg] = (mv && (l < ev[rg])) ? sacc[mi][ni][rg] : -FLT_MAX;
    }
#pragma unroll
    for (int rg = 0; rg < 4; ++rg) {
      float m = fmaxf(fmaxf(p[0][rg], p[1][rg]), fmaxf(p[2][rg], p[3][rg]));
      m = fmaxf(m, __shfl_xor(m, 1));
      m = fmaxf(m, __shfl_xor(m, 2));
      m = fmaxf(m, __shfl_xor(m, 4));
      m = fmaxf(m, __shfl_xor(m, 8));
      float sum = 0.f;
#pragma unroll
      for (int ni = 0; ni < 4; ++ni) {
        p[ni][rg] = __expf(p[ni][rg] - m);
        sum += p[ni][rg];
      }
      sum += __shfl_xor(sum, 1);
      sum += __shfl_xor(sum, 2);
      sum += __shfl_xor(sum, 4);
      sum += __shfl_xor(sum, 8);
      const float inv = 1.f / sum;
#pragma unroll
      for (int ni = 0; ni < 4; ++ni) p[ni][rg] *= inv;
    }
#pragma unroll
    for (int ni = 0; ni < 4; ++ni) {
      const int l = ni * 16 + fr;
#pragma unroll
      for (int rg = 0; rg < 4; ++rg) {
        const int row = mi * 16 + g * 4 + rg;
        QP[row * 64 + (((l >> 3) ^ (row & 7)) << 3) + (l & 7)] =
            (bf16)p[ni][rg];
      }
    }
  }

  // O = P @ V
  f32x4 oacc[4][4] = {};
#pragma unroll
  for (int ks = 0; ks < 2; ++ks) {
    bf16x8 pa[4], bv[4];
#pragma unroll
    for (int mi = 0; mi < 4; ++mi) {
      const int r = mi * 16 + fr;
      pa[mi] = *(const bf16x8*)&QP[r * 64 + ((((ks << 2) | g) ^ (r & 7)) << 3)];
    }
#pragma unroll
    for (int nd = 0; nd < 4; ++nd) {
      const int dh = nd * 16 + fr;
      bv[nd] = *(const bf16x8*)&Vlds[wc * 4096 + dh * 64 +
                                     ((((ks << 2) | g) ^ (dh & 7)) << 3)];
    }
#pragma unroll
    for (int mi = 0; mi < 4; ++mi)
#pragma unroll
      for (int nd = 0; nd < 4; ++nd)
        oacc[mi][nd] = __builtin_amdgcn_mfma_f32_16x16x32_bf16(
            pa[mi], bv[nd], oacc[mi][nd], 0, 0, 0);
  }
#pragma unroll
  for (int mi = 0; mi < 4; ++mi)
#pragma unroll
    for (int nd = 0; nd < 4; ++nd)
#pragma unroll
      for (int rg = 0; rg < 4; ++rg) {
        const size_t t = m0 + wr * 64 + mi * 16 + g * 4 + rg;
        aob[t * 512 + (2 * bx + wc) * 64 + nd * 16 + fr] =
            (bf16)oacc[mi][nd][rg];
      }
}

// ---------------------------------------------------------------------------
// Big GEMM (output projection) — unchanged R6 config (32x32x16, ring-3).
// ---------------------------------------------------------------------------
template <int OUT_BF16>
__global__ __launch_bounds__(512, 2) void gemm_big(
    const bf16* __restrict__ A, const bf16* __restrict__ Bt,
    void* __restrict__ Cv, int M, int N, int K) {
  __shared__ __align__(16) bf16 Abuf[3][256 * 64];
  __shared__ __align__(16) bf16 Bbuf[3][128 * 64];
  const int tid = threadIdx.x, lane = tid & 63;
  const int w = tid >> 6, wr = w >> 2, wc = w & 3;
  const int l31 = lane & 31, hi = lane >> 5;

  const int gx = gridDim.x;
  const int nwg = gx * gridDim.y;
  int lid = blockIdx.y * gx + blockIdx.x;
  {
    const int qq = nwg >> 3, rr = nwg & 7;
    const int xcd = lid & 7, pos = lid >> 3;
    lid = (xcd < rr ? xcd * (qq + 1) : rr * (qq + 1) + (xcd - rr) * qq) + pos;
  }
  const int bx = lid % gx, by = lid / gx;
  const size_t m0 = (size_t)by * 256, n0 = (size_t)bx * 128;

  const int nt = K >> 6;
  const int srow = tid >> 3;
  const int sslot = tid & 7;

  f32x16 acc[4] = {};

  auto stage = [&](int t) {
    const int s = t % 3;
    const int kt = t << 6;
#pragma unroll
    for (int c = 0; c < 4; ++c) {
      const int r = c * 64 + srow;
      gload_lds16(A + (m0 + r) * (size_t)K + kt + ((sslot ^ (r & 7)) << 3),
                  &Abuf[s][c * 4096 + w * 512]);
    }
#pragma unroll
    for (int c = 0; c < 2; ++c) {
      const int r = c * 64 + srow;
      gload_lds16(Bt + (n0 + r) * (size_t)K + kt + ((sslot ^ (r & 7)) << 3),
                  &Bbuf[s][c * 4096 + w * 512]);
    }
  };

  auto rdA = [&](int s, int mi, int ks) {
    const int r = wr * 128 + mi * 32 + l31;
    return *(const bf16x8*)&Abuf[s][r * 64 + ((((ks << 1) | hi) ^ (r & 7)) << 3)];
  };
  auto rdB = [&](int s, int ks) {
    const int r = wc * 32 + l31;
    return *(const bf16x8*)&Bbuf[s][r * 64 + ((((ks << 1) | hi) ^ (r & 7)) << 3)];
  };

  auto compute = [&](int t) {
    const int s = t % 3;
    bf16x8 bv[4];
#pragma unroll
    for (int ks = 0; ks < 4; ++ks) bv[ks] = rdB(s, ks);
    __builtin_amdgcn_s_setprio(1);
#pragma unroll
    for (int ks = 0; ks < 4; ++ks)
#pragma unroll
      for (int mi = 0; mi < 4; ++mi) {
        const bf16x8 av = rdA(s, mi, ks);
        acc[mi] = __builtin_amdgcn_mfma_f32_32x32x16_bf16(av, bv[ks], acc[mi],
                                                          0, 0, 0);
      }
    __builtin_amdgcn_s_setprio(0);
  };

  stage(0);
  stage(1);
  for (int t = 0; t < nt - 1; ++t) {
    __builtin_amdgcn_sched_barrier(0);
    asm volatile("s_waitcnt vmcnt(6)" ::: "memory");
    __builtin_amdgcn_s_barrier();
    __builtin_amdgcn_sched_barrier(0);
    if (t + 2 < nt) stage(t + 2);
    compute(t);
  }
  __builtin_amdgcn_sched_barrier(0);
  asm volatile("s_waitcnt vmcnt(0)" ::: "memory");
  __builtin_amdgcn_s_barrier();
  __builtin_amdgcn_sched_barrier(0);
  compute(nt - 1);

#pragma unroll
  for (int mi = 0; mi < 4; ++mi)
#pragma unroll
    for (int rg = 0; rg < 16; ++rg) {
      const size_t row =
          m0 + wr * 128 + mi * 32 + (rg & 3) + ((rg >> 2) << 3) + (hi << 2);
      const size_t col = n0 + wc * 32 + l31;
      if (OUT_BF16)
        ((bf16*)Cv)[row * (size_t)N + col] = (bf16)acc[mi][rg];
      else
        ((float*)Cv)[row * (size_t)N + col] = acc[mi][rg];
    }
}

// ---------------------------------------------------------------------------
// Small GEMM (KV projection): m97-style 128x128 tile, BK=32.
// ---------------------------------------------------------------------------
template <int OUT_BF16>
__global__ __launch_bounds__(256, 2) void gemm_bt(
    const bf16* __restrict__ A, const bf16* __restrict__ Bt,
    void* __restrict__ Cv, int M, int N, int K) {
  __shared__ bf16 As[128 * 32];
  __shared__ bf16 Bs[128 * 32];
  const int tid = threadIdx.x;
  const int lane = tid & 63, w = tid >> 6;
  const int wr = w >> 1, wc = w & 1;

  const int gx = gridDim.x;
  const int nwg = gx * gridDim.y;
  int lid = blockIdx.y * gx + blockIdx.x;
  {
    const int qq = nwg >> 3, rr = nwg & 7;
    const int xcd = lid & 7, pos = lid >> 3;
    lid = (xcd < rr ? xcd * (qq + 1) : rr * (qq + 1) + (xcd - rr) * qq) + pos;
  }
  const int bx = lid % gx, by = lid / gx;
  const size_t m0 = (size_t)by * 128, n0 = (size_t)bx * 128;

  const int srow = lane >> 2, sslot = lane & 3;
  const int g = lane >> 4, fr = lane & 15;

  f32x4 acc[4][4] = {};

  for (int kt = 0; kt < K; kt += 32) {
    __syncthreads();
#pragma unroll
    for (int j = 0; j < 2; ++j) {
      const int c = 2 * w + j;
      const int r = c * 16 + srow;
      const int ks = (sslot ^ (r & 3)) << 3;
      gload_lds16(A + (m0 + r) * K + kt + ks, &As[c * 512]);
      gload_lds16(Bt + (n0 + r) * K + kt + ks, &Bs[c * 512]);
    }
    __syncthreads();
    bf16x8 av[4], bv[4];
#pragma unroll
    for (int mi = 0; mi < 4; ++mi) {
      const int r = wr * 64 + mi * 16 + fr;
      av[mi] = *(const bf16x8*)&As[r * 32 + ((g ^ (r & 3)) << 3)];
    }
#pragma unroll
    for (int ni = 0; ni < 4; ++ni) {
      const int r = wc * 64 + ni * 16 + fr;
      bv[ni] = *(const bf16x8*)&Bs[r * 32 + ((g ^ (r & 3)) << 3)];
    }
#pragma unroll
    for (int mi = 0; mi < 4; ++mi)
#pragma unroll
      for (int ni = 0; ni < 4; ++ni)
        acc[mi][ni] = __builtin_amdgcn_mfma_f32_16x16x32_bf16(
            av[mi], bv[ni], acc[mi][ni], 0, 0, 0);
  }

#pragma unroll
  for (int mi = 0; mi < 4; ++mi)
#pragma unroll
    for (int ni = 0; ni < 4; ++ni)
#pragma unroll
      for (int rg = 0; rg < 4; ++rg) {
        const size_t row = m0 + wr * 64 + mi * 16 + g * 4 + rg;
        const size_t col = n0 + wc * 64 + ni * 16 + fr;
        if (OUT_BF16)
          ((bf16*)Cv)[row * (size_t)N + col] = (bf16)acc[mi][ni][rg];
        else
          ((float*)Cv)[row * (size_t)N + col] = acc[mi][ni][rg];
      }
}

// ---------------------------------------------------------------------------
// Coalesced 64x64 LDS-tiled transpose: dst[C][R] = src[R][C] * scale (bf16)
// ---------------------------------------------------------------------------
__device__ __forceinline__ void transp64(const float* __restrict__ src,
                                         bf16* __restrict__ dst, int R, int C,
                                         float scale, int tile, float* lds) {
  const int tilesC = C >> 6;
  const int tr = tile / tilesC, tc = tile % tilesC;
  const int r0 = tr << 6, c0 = tc << 6;
  const int tid = threadIdx.x;
  const int lr = tid >> 6, lc = tid & 63;
#pragma unroll
  for (int j = 0; j < 16; ++j) {
    const int r = j * 4 + lr;
    lds[r * 65 + lc] = src[(size_t)(r0 + r) * C + c0 + lc];
  }
  __syncthreads();
#pragma unroll
  for (int j = 0; j < 16; ++j) {
    const int rr = j * 4 + lr;  // dst row = src col
    dst[(size_t)(c0 + rr) * R + r0 + lc] = (bf16)(lds[lc * 65 + rr] * scale);
  }
}

// ---------------------------------------------------------------------------
// Mega prep kernel: one launch, block-range partitioned.
// ---------------------------------------------------------------------------
__global__ __launch_bounds__(256) void prep_all(
    const float* __restrict__ x, const float* __restrict__ gamma,
    const float* __restrict__ beta, bf16* __restrict__ xn,
    const float* __restrict__ Wq, bf16* __restrict__ wqT,
    const float* __restrict__ Wkv, bf16* __restrict__ wkvT,
    const float* __restrict__ Wout, bf16* __restrict__ woT,
    const float* __restrict__ media, bf16* __restrict__ medb,
    const int* __restrict__ mloc, int* __restrict__ endw,
    const unsigned char* __restrict__ mraw, int* __restrict__ mk) {
  __shared__ float shf[64 * 65];
  const int blk = blockIdx.x, tid = threadIdx.x;

  if (blk < 16384) {
    const size_t base = (size_t)blk * 2048 + tid * 8;
    f32x4 v0 = *(const f32x4*)(x + base);
    f32x4 v1 = *(const f32x4*)(x + base + 4);
    float s = 0.f, q2 = 0.f;
#pragma unroll
    for (int j = 0; j < 4; ++j) {
      s += v0[j] + v1[j];
      q2 += v0[j] * v0[j] + v1[j] * v1[j];
    }
    for (int off = 32; off > 0; off >>= 1) {
      s += __shfl_down(s, off);
      q2 += __shfl_down(q2, off);
    }
    const int lane = tid & 63, wv = tid >> 6;
    if (lane == 0) { shf[wv] = s; shf[4 + wv] = q2; }
    __syncthreads();
    s = shf[0] + shf[1] + shf[2] + shf[3];
    q2 = shf[4] + shf[5] + shf[6] + shf[7];
    const float mu = s * (1.f / 2048.f);
    const float var = q2 * (1.f / 2048.f) - mu * mu;
    const float rs = rsqrtf(var + 1e-5f);
    f32x4 g0 = *(const f32x4*)(gamma + tid * 8);
    f32x4 g1 = *(const f32x4*)(gamma + tid * 8 + 4);
    f32x4 b0 = *(const f32x4*)(beta + tid * 8);
    f32x4 b1 = *(const f32x4*)(beta + tid * 8 + 4);
    bf16x8 o;
#pragma unroll
    for (int j = 0; j < 4; ++j) {
      o[j] = (bf16)((v0[j] - mu) * rs * g0[j] + b0[j]);
      o[4 + j] = (bf16)((v1[j] - mu) * rs * g1[j] + b1[j]);
    }
    *(bf16x8*)(xn + base) = o;
  } else if (blk < 16640) {
    transp64(Wq, wqT, 2048, 512, 0.125f, blk - 16384, shf);
  } else if (blk < 16896) {
    transp64(Wkv, wkvT, 1024, 1024, 1.f, blk - 16640, shf);
  } else if (blk < 17152) {
    transp64(Wout, woT, 512, 2048, 1.f, blk - 16896, shf);
  } else if (blk < 18176) {
    const int i = (blk - 17152) * 256 + tid;
    medb[i] = (bf16)media[i];
  } else if (blk < 18180) {
    int* part = (int*)shf;
    const int b = blk - 18176;
    int loc[16];
    int s = 0;
    const int base = b * 4096 + tid * 16;
#pragma unroll
    for (int j = 0; j < 16; ++j) {
      loc[j] = (mloc[base + j] != 0) ? 1 : 0;
      s += loc[j];
    }
    part[tid] = s;
    __syncthreads();
    for (int off = 1; off < 256; off <<= 1) {
      int v = (tid >= off) ? part[tid - off] : 0;
      __syncthreads();
      part[tid] += v;
      __syncthreads();
    }
    int c = (tid > 0) ? part[tid - 1] : 0;
#pragma unroll
    for (int j = 0; j < 16; ++j) {
      c += loc[j];
      int e = (c > 1 ? c : 1) << 3;  // *W=8
      endw[base + j] = e > 64 ? 64 : e;
    }
  } else {
    int* isbool = (int*)shf;
    if (tid == 0) *isbool = 0;
    __syncthreads();
    const unsigned char v = mraw[tid];
    if ((tid & 3) != 0 && v != 0) atomicOr(isbool, 1);
    __syncthreads();
    mk[tid] = (*isbool) ? (int)mraw[tid] : ((const int*)mraw)[tid];
  }
}

// ---------------------------------------------------------------------------
extern "C" void kernel_launch(void* const* d_in, const int* in_sizes, int n_in,
                              void* d_out, int out_size, void* d_ws,
                              size_t ws_size, hipStream_t stream) {
  const float* x = (const float*)d_in[0];
  const float* media = (const float*)d_in[1];
  const unsigned char* mraw = (const unsigned char*)d_in[2];
  const int* mloc = (const int*)d_in[3];
  const float* Wq = (const float*)d_in[4];
  const float* Wkv = (const float*)d_in[5];
  const float* Wout = (const float*)d_in[6];
  const float* gamma = (const float*)d_in[7];
  const float* beta = (const float*)d_in[8];
  float* out = (float*)d_out;

  // xn (bf16, 67MB) lives in d_out scratch; dead before final GEMM overwrites.
  bf16* xn = (bf16*)d_out;

  char* ws = (char*)d_ws;
  size_t off = 0;
  auto carve = [&](size_t bytes) {
    void* p = ws + off;
    off += (bytes + 255) & ~(size_t)255;
    return p;
  };
  bf16* aob = (bf16*)carve((size_t)16384 * 512 * 2);
  bf16* kvb = (bf16*)carve((size_t)256 * 1024 * 2);
  bf16* wqT = (bf16*)carve((size_t)512 * 2048 * 2);
  bf16* wkvT = (bf16*)carve((size_t)1024 * 1024 * 2);
  bf16* woT = (bf16*)carve((size_t)2048 * 512 * 2);
  bf16* medb = (bf16*)carve((size_t)256 * 1024 * 2);
  int* endw = (int*)carve((size_t)4 * 4096 * 4);
  int* mk = (int*)carve(256 * 4);
  (void)ws_size;
  (void)in_sizes;
  (void)n_in;
  (void)out_size;

  // one fused prep pass (LN, 3 weight transposes, media cast, cumsum, mask)
  prep_all<<<18181, 256, 0, stream>>>(x, gamma, beta, xn, Wq, wqT, Wkv, wkvT,
                                      Wout, woT, media, medb, mloc, endw, mraw,
                                      mk);

  // KV projection (small)
  gemm_bt<1><<<dim3(8, 2), 256, 0, stream>>>(medb, wkvT, kvb, 256, 1024, 1024);

  // FUSED Q-projection + attention -> aob
  qattn<<<dim3(4, 64), 512, 0, stream>>>(xn, wqT, kvb, mk, endw, aob);

  // output projection (f32 out): grid 16 x 64 = 1024 blocks
  gemm_big<0><<<dim3(16, 64), 512, 0, stream>>>(aob, woT, out, 16384, 2048,
                                                512);
}